// Round 5
// baseline (468.646 us; speedup 1.0000x reference)
//
#include <hip/hip_runtime.h>
#include <hip/hip_bf16.h>

// Problem constants (B,N,C,NF) = (4,512,128,96)
#define NB 4
#define NN 512
#define CC 128

typedef __bf16 bf16x8 __attribute__((ext_vector_type(8)));
typedef __bf16 bf16x4 __attribute__((ext_vector_type(4)));
typedef float  f32x4  __attribute__((ext_vector_type(4)));

// LDS-only barrier: drains lgkmcnt but leaves global (weight) loads in flight.
__device__ __forceinline__ void barrier_lds() {
    __builtin_amdgcn_s_waitcnt(0xC07F);  // lgkmcnt(0), vmcnt/expcnt unrestricted
    __builtin_amdgcn_fence(__ATOMIC_RELEASE, "workgroup", "local");
    __builtin_amdgcn_s_barrier();
    __builtin_amdgcn_fence(__ATOMIC_ACQUIRE, "workgroup", "local");
}

__device__ __forceinline__ float lrelu(float v) { return fmaxf(v, 0.01f * v); }

__device__ __forceinline__ int pk4(float a, float b, float c, float d) {
    int p = __builtin_amdgcn_cvt_pk_fp8_f32(a, b, 0, false);
    return  __builtin_amdgcn_cvt_pk_fp8_f32(c, d, p, true);
}

// ---------- conversion prepass: x -> bf16; w1..w4 -> fp8 e4m3 ----------
__global__ void cvt_all(const float* __restrict__ x,  __bf16* __restrict__ xb,
                        const float* __restrict__ w1, int* __restrict__ w1f,
                        const float* __restrict__ w2, int* __restrict__ w2f,
                        const float* __restrict__ w3, int* __restrict__ w3f,
                        const float* __restrict__ w4, int* __restrict__ w4f)
{
    int idx = blockIdx.x * blockDim.x + threadIdx.x;
    if (idx < 65536) {                       // x: 262144 f32 -> bf16
        float4 v = ((const float4*)x)[idx];
        bf16x4 o = { (__bf16)v.x, (__bf16)v.y, (__bf16)v.z, (__bf16)v.w };
        ((bf16x4*)xb)[idx] = o;
    } else if (idx < 87808) {                // weights -> fp8 (4 f32 per int)
        const float* s; int* d; int off;
        if      (idx < 71680) { s = w1; d = w1f; off = idx - 65536; }  // 24576 f32
        else if (idx < 80896) { s = w2; d = w2f; off = idx - 71680; }  // 36864
        else if (idx < 85504) { s = w3; d = w3f; off = idx - 80896; }  // 18432
        else                  { s = w4; d = w4f; off = idx - 85504; }  //  9216
        float4 v = ((const float4*)s)[off];
        d[off] = pk4(v.x, v.y, v.z, v.w);
    }
}

// ---- weight fragment loader: 3 chunks of 16 out-channels, KC k-chunks ----
template<int KC, int WROW>
__device__ __forceinline__ void load_w(const unsigned char* __restrict__ wp,
                                       const float* __restrict__ bias,
                                       long long (&wv)[3][KC], f32x4 (&bv)[3],
                                       int chbase, int chstep, int l15, int q, int q8)
{
#pragma unroll
    for (int u = 0; u < 3; ++u) {
        const int ch = (chbase + u * chstep) * 16;
        bv[u] = *(const f32x4*)(bias + ch + q * 4);
#pragma unroll
        for (int k = 0; k < KC; ++k)
            wv[u][k] = *(const long long*)(wp + (size_t)(ch + l15) * WROW + k * 32 + q8);
    }
}

// ---- wide layer compute: this wave's nt-group (4 tiles), 3 chunks of 12 ----
template<int KC, int SIN, int SOUT>
__device__ __forceinline__ void wide_compute(const unsigned char* inB,
                                             unsigned char* outB,
                                             const long long (&wv)[3][KC],
                                             const f32x4 (&bv)[3],
                                             int l15, int q, int q8, int w4c, int g)
{
#pragma unroll
    for (int ntl = 0; ntl < 4; ++ntl) {
        const int nt = g * 4 + ntl;
        f32x4 acc[3] = { bv[0], bv[1], bv[2] };
        const unsigned char* inrow = inB + (nt * 16 + l15) * SIN + q8;
#pragma unroll
        for (int k = 0; k < KC; ++k) {
            long long bf = *(const long long*)(inrow + k * 32);
#pragma unroll
            for (int u = 0; u < 3; ++u)
                acc[u] = __builtin_amdgcn_mfma_f32_16x16x32_fp8_fp8(wv[u][k], bf, acc[u], 0, 0, 0);
        }
        unsigned char* orow = outB + (nt * 16 + l15) * SOUT + q * 4;
#pragma unroll
        for (int u = 0; u < 3; ++u)
            *(int*)(orow + (w4c + u * 4) * 16) =
                pk4(lrelu(acc[u][0]), lrelu(acc[u][1]), lrelu(acc[u][2]), lrelu(acc[u][3]));
    }
}

// ---------------- fused edge-MLP kernel -------------------------------------
// block: 128 edges = 8 i x 16 j, 512 threads (8 waves).
// Wide layers (L1,L2): wave (g = wave>>2, w4c = wave&3) -> nt tiles g*4..g*4+3,
//   channel chunks {w4c, w4c+4, w4c+8}.
// Narrow layers (L3,L4,L5): wave-LOCAL — wave owns nt = wave (16 edges) and
//   computes ALL channels; L3->L4 is a same-wave LDS dep (no barrier), L5
//   reduces via quad shfl (no cross-wave reduction at all).
// Barriers: 3 (d->L1, L1->L2, L2->L3).
// LDS: Abuf[128x200] (d stride 144 / h2 stride 200),
//      Bbuf[128x200] (h1 stride 200 / h3 stride 104) = 50 KB -> 3 blocks/CU.
__global__ __launch_bounds__(512, 6) void mlp_edges(
    const __bf16* __restrict__ xb,
    const unsigned char* __restrict__ w1p, const float* __restrict__ b1,
    const unsigned char* __restrict__ w2p, const float* __restrict__ b2,
    const unsigned char* __restrict__ w3p, const float* __restrict__ b3,
    const unsigned char* __restrict__ w4p, const float* __restrict__ b4,
    const float* __restrict__ w5,  const float* __restrict__ b5,
    float* __restrict__ out)
{
    __shared__ __align__(16) unsigned char AbufB[128 * 200];
    __shared__ __align__(16) unsigned char BbufB[128 * 200];

    const int t = threadIdx.x;
    const int lane = t & 63, wave = t >> 6;
    const int l15 = lane & 15, q = lane >> 4, q8 = q * 8;
    const int w4c = wave & 3, g = wave >> 2;
    const int j0 = blockIdx.x * 16, i0 = blockIdx.y * 8, b = blockIdx.z;

    // ---- JIT w1 + b1 (latency covered by d staging) ----
    long long w1v[3][4]; f32x4 b1v[3];
    load_w<4, 128>(w1p, b1, w1v, b1v, w4c, 4, l15, q, q8);

    // ---- stage d = |x_i - x_j| as fp8, 128 rows, stride 144 ----
    {
        const int m = t >> 2, c0 = (t & 3) * 32;
        const __bf16* xi = xb + ((size_t)b * NN + (i0 + (m >> 4))) * CC + c0;
        const __bf16* xj = xb + ((size_t)b * NN + (j0 + (m & 15))) * CC + c0;
        unsigned char* drow = AbufB + m * 144 + c0;
#pragma unroll
        for (int h = 0; h < 2; ++h) {
            bf16x8 a0  = *(const bf16x8*)(xi + h * 16);
            bf16x8 a1  = *(const bf16x8*)(xi + h * 16 + 8);
            bf16x8 c0v = *(const bf16x8*)(xj + h * 16);
            bf16x8 c1v = *(const bf16x8*)(xj + h * 16 + 8);
            float dv[16];
#pragma unroll
            for (int u = 0; u < 8; ++u) {
                dv[u]     = fabsf((float)a0[u] - (float)c0v[u]);
                dv[u + 8] = fabsf((float)a1[u] - (float)c1v[u]);
            }
            int4 pk;
            pk.x = pk4(dv[0],  dv[1],  dv[2],  dv[3]);
            pk.y = pk4(dv[4],  dv[5],  dv[6],  dv[7]);
            pk.z = pk4(dv[8],  dv[9],  dv[10], dv[11]);
            pk.w = pk4(dv[12], dv[13], dv[14], dv[15]);
            *(int4*)(drow + h * 16) = pk;
        }
    }

    barrier_lds();

    // ---- L1 (fp8): d(144) -> h1(200) ----
    wide_compute<4, 144, 200>(AbufB, BbufB, w1v, b1v, l15, q, q8, w4c, g);

    // ---- JIT w2 + b2 (in flight across barrier) ----
    long long w2v[3][6]; f32x4 b2v[3];
    load_w<6, 192>(w2p, b2, w2v, b2v, w4c, 4, l15, q, q8);

    barrier_lds();

    // ---- L2 (fp8): h1(200) -> h2(200) ----
    wide_compute<6, 200, 200>(BbufB, AbufB, w2v, b2v, l15, q, q8, w4c, g);

    // ---- JIT w3 grp0 (chunks 0..2), in flight across barrier ----
    long long w3v[3][6]; f32x4 b3v[3];
    load_w<6, 192>(w3p, b3, w3v, b3v, 0, 1, l15, q, q8);

    barrier_lds();

    // ---- L3 (fp8, wave-local): h2(200) -> h3(104), all 6 chunks ----
    long long ifr[6];
    {
        const unsigned char* inrow = AbufB + (wave * 16 + l15) * 200 + q8;
#pragma unroll
        for (int k = 0; k < 6; ++k) ifr[k] = *(const long long*)(inrow + k * 32);
    }
    unsigned char* h3row = BbufB + (wave * 16 + l15) * 104 + q * 4;
#pragma unroll
    for (int grp = 0; grp < 2; ++grp) {
        if (grp == 1) load_w<6, 192>(w3p, b3, w3v, b3v, 3, 1, l15, q, q8);
        f32x4 acc[3] = { b3v[0], b3v[1], b3v[2] };
#pragma unroll
        for (int k = 0; k < 6; ++k)
#pragma unroll
            for (int u = 0; u < 3; ++u)
                acc[u] = __builtin_amdgcn_mfma_f32_16x16x32_fp8_fp8(w3v[u][k], ifr[k], acc[u], 0, 0, 0);
#pragma unroll
        for (int u = 0; u < 3; ++u)
            *(int*)(h3row + (grp * 3 + u) * 16) =
                pk4(lrelu(acc[u][0]), lrelu(acc[u][1]), lrelu(acc[u][2]), lrelu(acc[u][3]));
    }

    // ---- L4 (fp8, wave-local) + L5 dot -> logit. Same-wave LDS dep only. ----
    __asm__ __volatile__("s_waitcnt lgkmcnt(0)" ::: "memory");
    long long hfr[3];
    {
        const unsigned char* inrow = BbufB + (wave * 16 + l15) * 104 + q8;
#pragma unroll
        for (int k = 0; k < 3; ++k) hfr[k] = *(const long long*)(inrow + k * 32);
    }
    float p = 0.f;
#pragma unroll
    for (int grp = 0; grp < 2; ++grp) {
        long long w4v[3][3]; f32x4 b4v[3];
        load_w<3, 96>(w4p, b4, w4v, b4v, grp * 3, 1, l15, q, q8);
        f32x4 w5v[3];
#pragma unroll
        for (int u = 0; u < 3; ++u)
            w5v[u] = *(const f32x4*)(w5 + (grp * 3 + u) * 16 + q * 4);
        f32x4 acc[3] = { b4v[0], b4v[1], b4v[2] };
#pragma unroll
        for (int k = 0; k < 3; ++k)
#pragma unroll
            for (int u = 0; u < 3; ++u)
                acc[u] = __builtin_amdgcn_mfma_f32_16x16x32_fp8_fp8(w4v[u][k], hfr[k], acc[u], 0, 0, 0);
#pragma unroll
        for (int u = 0; u < 3; ++u)
#pragma unroll
            for (int r = 0; r < 4; ++r)
                p += lrelu(acc[u][r]) * w5v[u][r];
    }
    p += __shfl_xor(p, 16, 64);   // combine quads (k-parts of the w5 dot)
    p += __shfl_xor(p, 32, 64);
    if (q == 0) {
        const int i = i0 + wave;
        const int j = j0 + l15;
        out[(((size_t)b * NN + i) * NN + j) * 2 + 1] = p + b5[0];
    }
}

// ---------------- softmax over j per (b,i) row, in place on out -------------
__global__ __launch_bounds__(256) void softmax_rows(float* __restrict__ out)
{
    const int row = blockIdx.x;           // b*512 + i
    const int i   = row & (NN - 1);
    float* base = out + (size_t)row * (NN * 2);
    const int t = threadIdx.x;

    float v0 = base[t * 2 + 1];
    float v1 = base[(t + 256) * 2 + 1];
    if (t == i)       v0 = -__builtin_inff();   // self-edge mask
    if (t + 256 == i) v1 = -__builtin_inff();

    float mx = fmaxf(v0, v1);
#pragma unroll
    for (int off = 32; off; off >>= 1) mx = fmaxf(mx, __shfl_xor(mx, off, 64));
    __shared__ float sm[4], ss[4];
    const int wave = t >> 6, lane = t & 63;
    if (lane == 0) sm[wave] = mx;
    __syncthreads();
    mx = fmaxf(fmaxf(sm[0], sm[1]), fmaxf(sm[2], sm[3]));

    const float e0 = __expf(v0 - mx), e1 = __expf(v1 - mx);
    float s = e0 + e1;
#pragma unroll
    for (int off = 32; off; off >>= 1) s += __shfl_xor(s, off, 64);
    if (lane == 0) ss[wave] = s;
    __syncthreads();
    s = ss[0] + ss[1] + ss[2] + ss[3];
    const float inv = 1.0f / s;

    float2* o2 = (float2*)base;
    o2[t]       = make_float2(t == i ? 1.f : 0.f,         e0 * inv);
    o2[t + 256] = make_float2((t + 256) == i ? 1.f : 0.f, e1 * inv);
}

// ---------------- host launch ----------------
extern "C" void kernel_launch(void* const* d_in, const int* in_sizes, int n_in,
                              void* d_out, int out_size, void* d_ws, size_t ws_size,
                              hipStream_t stream) {
    const float* x  = (const float*)d_in[0];
    // d_in[1] = W_id (pure eye broadcast; synthesized in-kernel)
    const float* w1 = (const float*)d_in[2];
    const float* b1 = (const float*)d_in[3];
    const float* w2 = (const float*)d_in[4];
    const float* b2 = (const float*)d_in[5];
    const float* w3 = (const float*)d_in[6];
    const float* b3 = (const float*)d_in[7];
    const float* w4 = (const float*)d_in[8];
    const float* b4 = (const float*)d_in[9];
    const float* w5 = (const float*)d_in[10];
    const float* b5 = (const float*)d_in[11];
    float* out = (float*)d_out;

    // ws: xb 524288 | w1f 24576 | w2f 36864 | w3f 18432 | w4f 9216
    char* ws = (char*)d_ws;
    __bf16*        xb  = (__bf16*)(ws);
    unsigned char* w1f = (unsigned char*)(ws + 524288);
    unsigned char* w2f = (unsigned char*)(ws + 548864);
    unsigned char* w3f = (unsigned char*)(ws + 585728);
    unsigned char* w4f = (unsigned char*)(ws + 604160);

    cvt_all<<<(87808 + 255) / 256, 256, 0, stream>>>(x, xb, w1, (int*)w1f,
                                                     w2, (int*)w2f, w3, (int*)w3f,
                                                     w4, (int*)w4f);

    dim3 grid(NN / 16, NN / 8, NB);   // j-tiles, i-tiles, batch
    mlp_edges<<<grid, 512, 0, stream>>>(xb, w1f, b1, w2f, b2, w3f, b3, w4f, b4,
                                        w5, b5, out);

    softmax_rows<<<NB * NN, 256, 0, stream>>>(out);
}

// Round 6
// 365.404 us; speedup vs baseline: 1.2825x; 1.2825x over previous
//
#include <hip/hip_runtime.h>
#include <hip/hip_bf16.h>

// Problem constants (B,N,C,NF) = (4,512,128,96)
#define NB 4
#define NN 512
#define CC 128

typedef __bf16 bf16x8 __attribute__((ext_vector_type(8)));
typedef __bf16 bf16x4 __attribute__((ext_vector_type(4)));
typedef float  f32x4  __attribute__((ext_vector_type(4)));
typedef int    i32x8  __attribute__((ext_vector_type(8)));

#define SCL 0x7F7F7F7F   // E8M0 127 (=1.0) in every byte — scale-neutral

// LDS-only barrier: drains lgkmcnt; global loads may stay in flight.
__device__ __forceinline__ void barrier_lds() {
    __builtin_amdgcn_s_waitcnt(0xC07F);
    __builtin_amdgcn_fence(__ATOMIC_RELEASE, "workgroup", "local");
    __builtin_amdgcn_s_barrier();
    __builtin_amdgcn_fence(__ATOMIC_ACQUIRE, "workgroup", "local");
}

__device__ __forceinline__ float lrelu(float v) { return fmaxf(v, 0.01f * v); }

__device__ __forceinline__ int pk4(float a, float b, float c, float d) {
    int p = __builtin_amdgcn_cvt_pk_fp8_f32(a, b, 0, false);
    return  __builtin_amdgcn_cvt_pk_fp8_f32(c, d, p, true);
}

// load 32 fp8 (8 dwords) from LDS via 4x b64 (rows only 8B-aligned)
__device__ __forceinline__ i32x8 ld_lds32(const unsigned char* p) {
    i32x8 r;
    long long* q = (long long*)&r;
    q[0] = *(const long long*)(p);
    q[1] = *(const long long*)(p + 8);
    q[2] = *(const long long*)(p + 16);
    q[3] = *(const long long*)(p + 24);
    return r;
}

// ---------- conversion prepass: x -> bf16; w1..w3 -> fp8; w4 -> fp8 padded K=128 ----------
__global__ void cvt_all(const float* __restrict__ x,  __bf16* __restrict__ xb,
                        const float* __restrict__ w1, int* __restrict__ w1f,
                        const float* __restrict__ w2, int* __restrict__ w2f,
                        const float* __restrict__ w3, int* __restrict__ w3f,
                        const float* __restrict__ w4, unsigned char* __restrict__ w4fp)
{
    int idx = blockIdx.x * blockDim.x + threadIdx.x;
    if (idx < 65536) {                       // x: 262144 f32 -> bf16
        float4 v = ((const float4*)x)[idx];
        bf16x4 o = { (__bf16)v.x, (__bf16)v.y, (__bf16)v.z, (__bf16)v.w };
        ((bf16x4*)xb)[idx] = o;
    } else if (idx < 85504) {                // w1..w3 -> fp8, packed rows
        const float* s; int* d; int off;
        if      (idx < 71680) { s = w1; d = w1f; off = idx - 65536; }  // 24576 f32
        else if (idx < 80896) { s = w2; d = w2f; off = idx - 71680; }  // 36864
        else                  { s = w3; d = w3f; off = idx - 80896; }  // 18432
        float4 v = ((const float4*)s)[off];
        d[off] = pk4(v.x, v.y, v.z, v.w);
    } else if (idx < 87808) {                // w4 -> fp8 into 128-wide rows
        int off = idx - 85504;               // 2304 float4s = 96 rows x 24
        int r = off / 24, c = (off % 24) * 4;
        float4 v = ((const float4*)w4)[off];
        *(int*)(w4fp + r * 128 + c) = pk4(v.x, v.y, v.z, v.w);
    } else if (idx < 88000) {                // zero-pad w4 rows, cols 96..127
        int p = idx - 87808;                 // 192 int4s
        int r = p >> 1;
        *(int4*)(w4fp + r * 128 + 96 + (p & 1) * 16) = make_int4(0, 0, 0, 0);
    }
}

// ---------------- fused edge-MLP kernel -------------------------------------
// R4 skeleton: 64 edges = 4 i x 16 j, 256 threads (4 waves), 5 LDS barriers.
// Orientation h^T = W * act^T; A = weights (regs, JIT per layer), B = acts
// (LDS). K=128-scaled MFMA (scale=1.0) shortens per-acc chains:
//   L1: 1 scaled          (K=128 exact)
//   L2/L3: 1 scaled + 2 regular (K=192 = 128 + 2x32)
//   L4: 1 scaled          (K=96 zero-padded to 128; w4 pre-padded)
// LDS: Abuf (d s136 / h2 s200), Bbuf (h1 s200 / h3 s136 padded) + red
//      = 26112 B -> 6 blocks/CU with __launch_bounds__(256,6).
__global__ __launch_bounds__(256, 6) void mlp_edges(
    const __bf16* __restrict__ xb,
    const unsigned char* __restrict__ w1p, const float* __restrict__ b1,
    const unsigned char* __restrict__ w2p, const float* __restrict__ b2,
    const unsigned char* __restrict__ w3p, const float* __restrict__ b3,
    const unsigned char* __restrict__ w4p, const float* __restrict__ b4,
    const float* __restrict__ w5,  const float* __restrict__ b5,
    float* __restrict__ out)
{
    __shared__ __align__(16) unsigned char AbufB[64 * 200];
    __shared__ __align__(16) unsigned char BbufB[64 * 200];
    __shared__ float red[128];

    const int t = threadIdx.x;
    const int lane = t & 63, wave = t >> 6;
    const int l15 = lane & 15, q = lane >> 4, q8 = q * 8, q32 = q * 32;
    const int j0 = blockIdx.x * 16, i0 = blockIdx.y * 4, b = blockIdx.z;

    // ---- JIT w1 (K=128 scaled A-frag: 32B/lane) + b1 ----
    i32x8 w1v[3]; f32x4 b1v[3];
#pragma unroll
    for (int u = 0; u < 3; ++u) {
        const int ch = (wave + u * 4) * 16;
        b1v[u] = *(const f32x4*)(b1 + ch + q * 4);
        w1v[u] = *(const i32x8*)(w1p + (size_t)(ch + l15) * 128 + q32);
    }
    __builtin_amdgcn_sched_barrier(0);   // don't sink the loads past the barrier

    // ---- stage d = |x_i - x_j| as fp8, stride 136 ----
    {
        const int m = t >> 2, c0 = (t & 3) * 32;
        const __bf16* xi = xb + ((size_t)b * NN + (i0 + (m >> 4))) * CC + c0;
        const __bf16* xj = xb + ((size_t)b * NN + (j0 + (m & 15))) * CC + c0;
        unsigned char* drow = AbufB + m * 136 + c0;
#pragma unroll
        for (int h = 0; h < 2; ++h) {
            bf16x8 a0  = *(const bf16x8*)(xi + h * 16);
            bf16x8 a1  = *(const bf16x8*)(xi + h * 16 + 8);
            bf16x8 c0v = *(const bf16x8*)(xj + h * 16);
            bf16x8 c1v = *(const bf16x8*)(xj + h * 16 + 8);
            float dv[16];
#pragma unroll
            for (int u = 0; u < 8; ++u) {
                dv[u]     = fabsf((float)a0[u] - (float)c0v[u]);
                dv[u + 8] = fabsf((float)a1[u] - (float)c1v[u]);
            }
            int2 lo = make_int2(pk4(dv[0], dv[1], dv[2],  dv[3]),
                                pk4(dv[4], dv[5], dv[6],  dv[7]));
            int2 hi = make_int2(pk4(dv[8], dv[9], dv[10], dv[11]),
                                pk4(dv[12], dv[13], dv[14], dv[15]));
            *(int2*)(drow + h * 16)     = lo;
            *(int2*)(drow + h * 16 + 8) = hi;
        }
    }

    barrier_lds();

    // ---- L1: d(136) -> h1(200); 1 scaled MFMA per acc ----
#pragma unroll
    for (int nt = 0; nt < 4; ++nt) {
        i32x8 bfs = ld_lds32(AbufB + (nt * 16 + l15) * 136 + q32);
        f32x4 acc[3] = { b1v[0], b1v[1], b1v[2] };
#pragma unroll
        for (int u = 0; u < 3; ++u)
            acc[u] = __builtin_amdgcn_mfma_scale_f32_16x16x128_f8f6f4(
                         w1v[u], bfs, acc[u], 0, 0, 0, SCL, 0, SCL);
        unsigned char* orow = BbufB + (nt * 16 + l15) * 200 + q * 4;
#pragma unroll
        for (int u = 0; u < 3; ++u)
            *(int*)(orow + (wave + u * 4) * 16) =
                pk4(lrelu(acc[u][0]), lrelu(acc[u][1]), lrelu(acc[u][2]), lrelu(acc[u][3]));
    }

    // ---- JIT w2 (K=192: scaled 128 + 2x32) + b2 ----
    i32x8 w2s[3]; long long w2r[3][2]; f32x4 b2v[3];
#pragma unroll
    for (int u = 0; u < 3; ++u) {
        const int ch = (wave + u * 4) * 16;
        b2v[u] = *(const f32x4*)(b2 + ch + q * 4);
        const unsigned char* wrow = w2p + (size_t)(ch + l15) * 192;
        w2s[u] = *(const i32x8*)(wrow + q32);
        w2r[u][0] = *(const long long*)(wrow + 128 + q8);
        w2r[u][1] = *(const long long*)(wrow + 160 + q8);
    }
    __builtin_amdgcn_sched_barrier(0);

    barrier_lds();

    // ---- L2: h1(200) -> h2(200) ----
#pragma unroll
    for (int nt = 0; nt < 4; ++nt) {
        const unsigned char* inrow = BbufB + (nt * 16 + l15) * 200;
        i32x8 bfs = ld_lds32(inrow + q32);
        long long bfr0 = *(const long long*)(inrow + 128 + q8);
        long long bfr1 = *(const long long*)(inrow + 160 + q8);
        f32x4 acc[3] = { b2v[0], b2v[1], b2v[2] };
#pragma unroll
        for (int u = 0; u < 3; ++u) {
            acc[u] = __builtin_amdgcn_mfma_scale_f32_16x16x128_f8f6f4(
                         w2s[u], bfs, acc[u], 0, 0, 0, SCL, 0, SCL);
            acc[u] = __builtin_amdgcn_mfma_f32_16x16x32_fp8_fp8(w2r[u][0], bfr0, acc[u], 0, 0, 0);
            acc[u] = __builtin_amdgcn_mfma_f32_16x16x32_fp8_fp8(w2r[u][1], bfr1, acc[u], 0, 0, 0);
        }
        unsigned char* orow = AbufB + (nt * 16 + l15) * 200 + q * 4;
#pragma unroll
        for (int u = 0; u < 3; ++u)
            *(int*)(orow + (wave + u * 4) * 16) =
                pk4(lrelu(acc[u][0]), lrelu(acc[u][1]), lrelu(acc[u][2]), lrelu(acc[u][3]));
    }

    // ---- JIT w3 (narrow split) + b3 ----
    const int mc0n = (wave & 1) * 3;      // narrow: ch chunks
    const int nlo  = (wave >> 1) * 2;     // narrow: edge tiles
    i32x8 w3s[3]; long long w3r[3][2]; f32x4 b3v[3];
#pragma unroll
    for (int u = 0; u < 3; ++u) {
        const int ch = (mc0n + u) * 16;
        b3v[u] = *(const f32x4*)(b3 + ch + q * 4);
        const unsigned char* wrow = w3p + (size_t)(ch + l15) * 192;
        w3s[u] = *(const i32x8*)(wrow + q32);
        w3r[u][0] = *(const long long*)(wrow + 128 + q8);
        w3r[u][1] = *(const long long*)(wrow + 160 + q8);
    }
    __builtin_amdgcn_sched_barrier(0);

    barrier_lds();

    // zero-pad h3 cols 96..127 (stride-136 rows in Bbuf; h1 is dead now)
    *(long long*)(BbufB + (t >> 2) * 136 + 96 + (t & 3) * 8) = 0;

    // ---- L3: h2(200) -> h3(136, K-padded) ----
#pragma unroll
    for (int ntl = 0; ntl < 2; ++ntl) {
        const int nt = nlo + ntl;
        const unsigned char* inrow = AbufB + (nt * 16 + l15) * 200;
        i32x8 bfs = ld_lds32(inrow + q32);
        long long bfr0 = *(const long long*)(inrow + 128 + q8);
        long long bfr1 = *(const long long*)(inrow + 160 + q8);
        f32x4 acc[3] = { b3v[0], b3v[1], b3v[2] };
#pragma unroll
        for (int u = 0; u < 3; ++u) {
            acc[u] = __builtin_amdgcn_mfma_scale_f32_16x16x128_f8f6f4(
                         w3s[u], bfs, acc[u], 0, 0, 0, SCL, 0, SCL);
            acc[u] = __builtin_amdgcn_mfma_f32_16x16x32_fp8_fp8(w3r[u][0], bfr0, acc[u], 0, 0, 0);
            acc[u] = __builtin_amdgcn_mfma_f32_16x16x32_fp8_fp8(w3r[u][1], bfr1, acc[u], 0, 0, 0);
        }
        unsigned char* orow = BbufB + (nt * 16 + l15) * 136 + q * 4;
#pragma unroll
        for (int u = 0; u < 3; ++u)
            *(int*)(orow + (mc0n + u) * 16) =
                pk4(lrelu(acc[u][0]), lrelu(acc[u][1]), lrelu(acc[u][2]), lrelu(acc[u][3]));
    }

    // ---- JIT w4 (padded K=128 scaled) + b4 + w5 ----
    i32x8 w4s[3]; f32x4 b4v[3], w5v[3];
#pragma unroll
    for (int u = 0; u < 3; ++u) {
        const int ch = (mc0n + u) * 16;
        b4v[u] = *(const f32x4*)(b4 + ch + q * 4);
        w5v[u] = *(const f32x4*)(w5 + ch + q * 4);
        w4s[u] = *(const i32x8*)(w4p + (size_t)(ch + l15) * 128 + q32);
    }
    __builtin_amdgcn_sched_barrier(0);

    barrier_lds();

    // ---- L4 (1 scaled MFMA per acc) + L5 dot -> logit ----
#pragma unroll
    for (int ntl = 0; ntl < 2; ++ntl) {
        const int nt = nlo + ntl;
        i32x8 bfs = ld_lds32(BbufB + (nt * 16 + l15) * 136 + q32);
        f32x4 acc[3] = { b4v[0], b4v[1], b4v[2] };
#pragma unroll
        for (int u = 0; u < 3; ++u)
            acc[u] = __builtin_amdgcn_mfma_scale_f32_16x16x128_f8f6f4(
                         w4s[u], bfs, acc[u], 0, 0, 0, SCL, 0, SCL);
        float p = 0.f;
#pragma unroll
        for (int u = 0; u < 3; ++u)
#pragma unroll
            for (int r = 0; r < 4; ++r)
                p += lrelu(acc[u][r]) * w5v[u][r];
        p += __shfl_xor(p, 16, 64);   // combine quads (k-parts of w5 dot)
        p += __shfl_xor(p, 32, 64);
        if (q == 0) red[(wave * 2 + ntl) * 16 + l15] = p;
    }

    barrier_lds();

    if ((wave & 1) == 0 && lane < 32) {
        const int ntl = lane >> 4, e = lane & 15;
        const float logit = red[(wave * 2 + ntl) * 16 + e]
                          + red[((wave + 1) * 2 + ntl) * 16 + e] + b5[0];
        const int i = i0 + (wave >> 1) * 2 + ntl;
        const int j = j0 + e;
        out[(((size_t)b * NN + i) * NN + j) * 2 + 1] = logit;
    }
}

// ---------------- softmax over j per (b,i) row, in place on out -------------
__global__ __launch_bounds__(256) void softmax_rows(float* __restrict__ out)
{
    const int row = blockIdx.x;           // b*512 + i
    const int i   = row & (NN - 1);
    float* base = out + (size_t)row * (NN * 2);
    const int t = threadIdx.x;

    float v0 = base[t * 2 + 1];
    float v1 = base[(t + 256) * 2 + 1];
    if (t == i)       v0 = -__builtin_inff();   // self-edge mask
    if (t + 256 == i) v1 = -__builtin_inff();

    float mx = fmaxf(v0, v1);
#pragma unroll
    for (int off = 32; off; off >>= 1) mx = fmaxf(mx, __shfl_xor(mx, off, 64));
    __shared__ float sm[4], ss[4];
    const int wave = t >> 6, lane = t & 63;
    if (lane == 0) sm[wave] = mx;
    __syncthreads();
    mx = fmaxf(fmaxf(sm[0], sm[1]), fmaxf(sm[2], sm[3]));

    const float e0 = __expf(v0 - mx), e1 = __expf(v1 - mx);
    float s = e0 + e1;
#pragma unroll
    for (int off = 32; off; off >>= 1) s += __shfl_xor(s, off, 64);
    if (lane == 0) ss[wave] = s;
    __syncthreads();
    s = ss[0] + ss[1] + ss[2] + ss[3];
    const float inv = 1.0f / s;

    float2* o2 = (float2*)base;
    o2[t]       = make_float2(t == i ? 1.f : 0.f,         e0 * inv);
    o2[t + 256] = make_float2((t + 256) == i ? 1.f : 0.f, e1 * inv);
}

// ---------------- host launch ----------------
extern "C" void kernel_launch(void* const* d_in, const int* in_sizes, int n_in,
                              void* d_out, int out_size, void* d_ws, size_t ws_size,
                              hipStream_t stream) {
    const float* x  = (const float*)d_in[0];
    // d_in[1] = W_id (pure eye broadcast; synthesized in-kernel)
    const float* w1 = (const float*)d_in[2];
    const float* b1 = (const float*)d_in[3];
    const float* w2 = (const float*)d_in[4];
    const float* b2 = (const float*)d_in[5];
    const float* w3 = (const float*)d_in[6];
    const float* b3 = (const float*)d_in[7];
    const float* w4 = (const float*)d_in[8];
    const float* b4 = (const float*)d_in[9];
    const float* w5 = (const float*)d_in[10];
    const float* b5 = (const float*)d_in[11];
    float* out = (float*)d_out;

    // ws: xb 524288 | w1f 24576 | w2f 36864 | w3f 18432 | w4fp 12288 (96x128 padded)
    char* ws = (char*)d_ws;
    __bf16*        xb   = (__bf16*)(ws);
    unsigned char* w1f  = (unsigned char*)(ws + 524288);
    unsigned char* w2f  = (unsigned char*)(ws + 548864);
    unsigned char* w3f  = (unsigned char*)(ws + 585728);
    unsigned char* w4fp = (unsigned char*)(ws + 604160);

    cvt_all<<<(88000 + 255) / 256, 256, 0, stream>>>(x, xb, w1, (int*)w1f,
                                                     w2, (int*)w2f, w3, (int*)w3f,
                                                     w4, w4fp);

    dim3 grid(NN / 16, NN / 4, NB);   // j-tiles, i-tiles, batch
    mlp_edges<<<grid, 256, 0, stream>>>(xb, w1f, b1, w2f, b2, w3f, b3, w4fp, b4,
                                        w5, b5, out);

    softmax_rows<<<NB * NN, 256, 0, stream>>>(out);
}

// Round 7
// 311.738 us; speedup vs baseline: 1.5033x; 1.1722x over previous
//
#include <hip/hip_runtime.h>
#include <hip/hip_bf16.h>

// Problem constants (B,N,C,NF) = (4,512,128,96)
#define NB 4
#define NN 512
#define CC 128

typedef __bf16 bf16x8 __attribute__((ext_vector_type(8)));
typedef __bf16 bf16x4 __attribute__((ext_vector_type(4)));
typedef float  f32x4  __attribute__((ext_vector_type(4)));
typedef int    i32x8  __attribute__((ext_vector_type(8)));

#define SCL 0x7F7F7F7F   // E8M0 127 (=1.0) in every byte — scale-neutral

// LDS-only barrier: drains lgkmcnt; global loads may stay in flight.
__device__ __forceinline__ void barrier_lds() {
    __builtin_amdgcn_s_waitcnt(0xC07F);
    __builtin_amdgcn_fence(__ATOMIC_RELEASE, "workgroup", "local");
    __builtin_amdgcn_s_barrier();
    __builtin_amdgcn_fence(__ATOMIC_ACQUIRE, "workgroup", "local");
}

__device__ __forceinline__ float lrelu(float v) { return fmaxf(v, 0.01f * v); }

__device__ __forceinline__ int pk4(float a, float b, float c, float d) {
    int p = __builtin_amdgcn_cvt_pk_fp8_f32(a, b, 0, false);
    return  __builtin_amdgcn_cvt_pk_fp8_f32(c, d, p, true);
}

// load 32 fp8 (8 dwords) from LDS via 4x b64 (rows only 8B-aligned)
__device__ __forceinline__ i32x8 ld_lds32(const unsigned char* p) {
    i32x8 r;
    long long* q = (long long*)&r;
    q[0] = *(const long long*)(p);
    q[1] = *(const long long*)(p + 8);
    q[2] = *(const long long*)(p + 16);
    q[3] = *(const long long*)(p + 24);
    return r;
}

// ---------- conversion prepass: x -> bf16; w1..w3 -> fp8; w4 -> fp8 padded K=128 ----------
__global__ void cvt_all(const float* __restrict__ x,  __bf16* __restrict__ xb,
                        const float* __restrict__ w1, int* __restrict__ w1f,
                        const float* __restrict__ w2, int* __restrict__ w2f,
                        const float* __restrict__ w3, int* __restrict__ w3f,
                        const float* __restrict__ w4, unsigned char* __restrict__ w4fp)
{
    int idx = blockIdx.x * blockDim.x + threadIdx.x;
    if (idx < 65536) {                       // x: 262144 f32 -> bf16
        float4 v = ((const float4*)x)[idx];
        bf16x4 o = { (__bf16)v.x, (__bf16)v.y, (__bf16)v.z, (__bf16)v.w };
        ((bf16x4*)xb)[idx] = o;
    } else if (idx < 85504) {                // w1..w3 -> fp8, packed rows
        const float* s; int* d; int off;
        if      (idx < 71680) { s = w1; d = w1f; off = idx - 65536; }  // 24576 f32
        else if (idx < 80896) { s = w2; d = w2f; off = idx - 71680; }  // 36864
        else                  { s = w3; d = w3f; off = idx - 80896; }  // 18432
        float4 v = ((const float4*)s)[off];
        d[off] = pk4(v.x, v.y, v.z, v.w);
    } else if (idx < 87808) {                // w4 -> fp8 into 128-wide rows
        int off = idx - 85504;               // 2304 float4s = 96 rows x 24
        int r = off / 24, c = (off % 24) * 4;
        float4 v = ((const float4*)w4)[off];
        *(int*)(w4fp + r * 128 + c) = pk4(v.x, v.y, v.z, v.w);
    } else if (idx < 88000) {                // zero-pad w4 rows, cols 96..127
        int p = idx - 87808;                 // 192 int4s
        int r = p >> 1;
        *(int4*)(w4fp + r * 128 + 96 + (p & 1) * 16) = make_int4(0, 0, 0, 0);
    }
}

// ---------------- fused edge-MLP kernel -------------------------------------
// R4 skeleton: 64 edges = 4 i x 16 j, 256 threads (4 waves), 5 LDS barriers.
// Orientation h^T = W * act^T; A = weights (regs, JIT per layer), B = acts
// (LDS). K=128-scaled MFMA (scale=1.0) shortens per-acc chains:
//   L1: 1 scaled          (K=128 exact)
//   L2/L3: 1 scaled + 2 regular (K=192 = 128 + 2x32)
//   L4: 1 scaled          (K=96 zero-padded to 128; w4 pre-padded)
// __launch_bounds__(256,4): VGPR cap 128 — the v8i32 mfma_scale operand
// tuples need ~100 live regs; the (256,6)/85-cap variant spilled 408 MB to
// scratch (R6). LDS 26112 B would allow 6 blocks/CU; VGPRs set residency.
__global__ __launch_bounds__(256, 4) void mlp_edges(
    const __bf16* __restrict__ xb,
    const unsigned char* __restrict__ w1p, const float* __restrict__ b1,
    const unsigned char* __restrict__ w2p, const float* __restrict__ b2,
    const unsigned char* __restrict__ w3p, const float* __restrict__ b3,
    const unsigned char* __restrict__ w4p, const float* __restrict__ b4,
    const float* __restrict__ w5,  const float* __restrict__ b5,
    float* __restrict__ out)
{
    __shared__ __align__(16) unsigned char AbufB[64 * 200];
    __shared__ __align__(16) unsigned char BbufB[64 * 200];
    __shared__ float red[128];

    const int t = threadIdx.x;
    const int lane = t & 63, wave = t >> 6;
    const int l15 = lane & 15, q = lane >> 4, q8 = q * 8, q32 = q * 32;
    const int j0 = blockIdx.x * 16, i0 = blockIdx.y * 4, b = blockIdx.z;

    // ---- JIT w1 (K=128 scaled A-frag: 32B/lane) + b1 ----
    i32x8 w1v[3]; f32x4 b1v[3];
#pragma unroll
    for (int u = 0; u < 3; ++u) {
        const int ch = (wave + u * 4) * 16;
        b1v[u] = *(const f32x4*)(b1 + ch + q * 4);
        w1v[u] = *(const i32x8*)(w1p + (size_t)(ch + l15) * 128 + q32);
    }
    __builtin_amdgcn_sched_barrier(0);   // don't sink the loads past the barrier

    // ---- stage d = |x_i - x_j| as fp8, stride 136 ----
    {
        const int m = t >> 2, c0 = (t & 3) * 32;
        const __bf16* xi = xb + ((size_t)b * NN + (i0 + (m >> 4))) * CC + c0;
        const __bf16* xj = xb + ((size_t)b * NN + (j0 + (m & 15))) * CC + c0;
        unsigned char* drow = AbufB + m * 136 + c0;
#pragma unroll
        for (int h = 0; h < 2; ++h) {
            bf16x8 a0  = *(const bf16x8*)(xi + h * 16);
            bf16x8 a1  = *(const bf16x8*)(xi + h * 16 + 8);
            bf16x8 c0v = *(const bf16x8*)(xj + h * 16);
            bf16x8 c1v = *(const bf16x8*)(xj + h * 16 + 8);
            float dv[16];
#pragma unroll
            for (int u = 0; u < 8; ++u) {
                dv[u]     = fabsf((float)a0[u] - (float)c0v[u]);
                dv[u + 8] = fabsf((float)a1[u] - (float)c1v[u]);
            }
            int2 lo = make_int2(pk4(dv[0], dv[1], dv[2],  dv[3]),
                                pk4(dv[4], dv[5], dv[6],  dv[7]));
            int2 hi = make_int2(pk4(dv[8], dv[9], dv[10], dv[11]),
                                pk4(dv[12], dv[13], dv[14], dv[15]));
            *(int2*)(drow + h * 16)     = lo;
            *(int2*)(drow + h * 16 + 8) = hi;
        }
    }

    barrier_lds();

    // ---- L1: d(136) -> h1(200); 1 scaled MFMA per acc ----
#pragma unroll
    for (int nt = 0; nt < 4; ++nt) {
        i32x8 bfs = ld_lds32(AbufB + (nt * 16 + l15) * 136 + q32);
        f32x4 acc[3] = { b1v[0], b1v[1], b1v[2] };
#pragma unroll
        for (int u = 0; u < 3; ++u)
            acc[u] = __builtin_amdgcn_mfma_scale_f32_16x16x128_f8f6f4(
                         w1v[u], bfs, acc[u], 0, 0, 0, SCL, 0, SCL);
        unsigned char* orow = BbufB + (nt * 16 + l15) * 200 + q * 4;
#pragma unroll
        for (int u = 0; u < 3; ++u)
            *(int*)(orow + (wave + u * 4) * 16) =
                pk4(lrelu(acc[u][0]), lrelu(acc[u][1]), lrelu(acc[u][2]), lrelu(acc[u][3]));
    }

    // ---- JIT w2 (K=192: scaled 128 + 2x32) + b2 ----
    i32x8 w2s[3]; long long w2r[3][2]; f32x4 b2v[3];
#pragma unroll
    for (int u = 0; u < 3; ++u) {
        const int ch = (wave + u * 4) * 16;
        b2v[u] = *(const f32x4*)(b2 + ch + q * 4);
        const unsigned char* wrow = w2p + (size_t)(ch + l15) * 192;
        w2s[u] = *(const i32x8*)(wrow + q32);
        w2r[u][0] = *(const long long*)(wrow + 128 + q8);
        w2r[u][1] = *(const long long*)(wrow + 160 + q8);
    }
    __builtin_amdgcn_sched_barrier(0);

    barrier_lds();

    // ---- L2: h1(200) -> h2(200) ----
#pragma unroll
    for (int nt = 0; nt < 4; ++nt) {
        const unsigned char* inrow = BbufB + (nt * 16 + l15) * 200;
        i32x8 bfs = ld_lds32(inrow + q32);
        long long bfr0 = *(const long long*)(inrow + 128 + q8);
        long long bfr1 = *(const long long*)(inrow + 160 + q8);
        f32x4 acc[3] = { b2v[0], b2v[1], b2v[2] };
#pragma unroll
        for (int u = 0; u < 3; ++u) {
            acc[u] = __builtin_amdgcn_mfma_scale_f32_16x16x128_f8f6f4(
                         w2s[u], bfs, acc[u], 0, 0, 0, SCL, 0, SCL);
            acc[u] = __builtin_amdgcn_mfma_f32_16x16x32_fp8_fp8(w2r[u][0], bfr0, acc[u], 0, 0, 0);
            acc[u] = __builtin_amdgcn_mfma_f32_16x16x32_fp8_fp8(w2r[u][1], bfr1, acc[u], 0, 0, 0);
        }
        unsigned char* orow = AbufB + (nt * 16 + l15) * 200 + q * 4;
#pragma unroll
        for (int u = 0; u < 3; ++u)
            *(int*)(orow + (wave + u * 4) * 16) =
                pk4(lrelu(acc[u][0]), lrelu(acc[u][1]), lrelu(acc[u][2]), lrelu(acc[u][3]));
    }

    // ---- JIT w3 (narrow split) + b3 ----
    const int mc0n = (wave & 1) * 3;      // narrow: ch chunks
    const int nlo  = (wave >> 1) * 2;     // narrow: edge tiles
    i32x8 w3s[3]; long long w3r[3][2]; f32x4 b3v[3];
#pragma unroll
    for (int u = 0; u < 3; ++u) {
        const int ch = (mc0n + u) * 16;
        b3v[u] = *(const f32x4*)(b3 + ch + q * 4);
        const unsigned char* wrow = w3p + (size_t)(ch + l15) * 192;
        w3s[u] = *(const i32x8*)(wrow + q32);
        w3r[u][0] = *(const long long*)(wrow + 128 + q8);
        w3r[u][1] = *(const long long*)(wrow + 160 + q8);
    }
    __builtin_amdgcn_sched_barrier(0);

    barrier_lds();

    // zero-pad h3 cols 96..127 (stride-136 rows in Bbuf; h1 is dead now)
    *(long long*)(BbufB + (t >> 2) * 136 + 96 + (t & 3) * 8) = 0;

    // ---- L3: h2(200) -> h3(136, K-padded) ----
#pragma unroll
    for (int ntl = 0; ntl < 2; ++ntl) {
        const int nt = nlo + ntl;
        const unsigned char* inrow = AbufB + (nt * 16 + l15) * 200;
        i32x8 bfs = ld_lds32(inrow + q32);
        long long bfr0 = *(const long long*)(inrow + 128 + q8);
        long long bfr1 = *(const long long*)(inrow + 160 + q8);
        f32x4 acc[3] = { b3v[0], b3v[1], b3v[2] };
#pragma unroll
        for (int u = 0; u < 3; ++u) {
            acc[u] = __builtin_amdgcn_mfma_scale_f32_16x16x128_f8f6f4(
                         w3s[u], bfs, acc[u], 0, 0, 0, SCL, 0, SCL);
            acc[u] = __builtin_amdgcn_mfma_f32_16x16x32_fp8_fp8(w3r[u][0], bfr0, acc[u], 0, 0, 0);
            acc[u] = __builtin_amdgcn_mfma_f32_16x16x32_fp8_fp8(w3r[u][1], bfr1, acc[u], 0, 0, 0);
        }
        unsigned char* orow = BbufB + (nt * 16 + l15) * 136 + q * 4;
#pragma unroll
        for (int u = 0; u < 3; ++u)
            *(int*)(orow + (mc0n + u) * 16) =
                pk4(lrelu(acc[u][0]), lrelu(acc[u][1]), lrelu(acc[u][2]), lrelu(acc[u][3]));
    }

    // ---- JIT w4 (padded K=128 scaled) + b4 + w5 ----
    i32x8 w4s[3]; f32x4 b4v[3], w5v[3];
#pragma unroll
    for (int u = 0; u < 3; ++u) {
        const int ch = (mc0n + u) * 16;
        b4v[u] = *(const f32x4*)(b4 + ch + q * 4);
        w5v[u] = *(const f32x4*)(w5 + ch + q * 4);
        w4s[u] = *(const i32x8*)(w4p + (size_t)(ch + l15) * 128 + q32);
    }
    __builtin_amdgcn_sched_barrier(0);

    barrier_lds();

    // ---- L4 (1 scaled MFMA per acc) + L5 dot -> logit ----
#pragma unroll
    for (int ntl = 0; ntl < 2; ++ntl) {
        const int nt = nlo + ntl;
        i32x8 bfs = ld_lds32(BbufB + (nt * 16 + l15) * 136 + q32);
        f32x4 acc[3] = { b4v[0], b4v[1], b4v[2] };
#pragma unroll
        for (int u = 0; u < 3; ++u)
            acc[u] = __builtin_amdgcn_mfma_scale_f32_16x16x128_f8f6f4(
                         w4s[u], bfs, acc[u], 0, 0, 0, SCL, 0, SCL);
        float p = 0.f;
#pragma unroll
        for (int u = 0; u < 3; ++u)
#pragma unroll
            for (int r = 0; r < 4; ++r)
                p += lrelu(acc[u][r]) * w5v[u][r];
        p += __shfl_xor(p, 16, 64);   // combine quads (k-parts of w5 dot)
        p += __shfl_xor(p, 32, 64);
        if (q == 0) red[(wave * 2 + ntl) * 16 + l15] = p;
    }

    barrier_lds();

    if ((wave & 1) == 0 && lane < 32) {
        const int ntl = lane >> 4, e = lane & 15;
        const float logit = red[(wave * 2 + ntl) * 16 + e]
                          + red[((wave + 1) * 2 + ntl) * 16 + e] + b5[0];
        const int i = i0 + (wave >> 1) * 2 + ntl;
        const int j = j0 + e;
        out[(((size_t)b * NN + i) * NN + j) * 2 + 1] = logit;
    }
}

// ---------------- softmax over j per (b,i) row, in place on out -------------
__global__ __launch_bounds__(256) void softmax_rows(float* __restrict__ out)
{
    const int row = blockIdx.x;           // b*512 + i
    const int i   = row & (NN - 1);
    float* base = out + (size_t)row * (NN * 2);
    const int t = threadIdx.x;

    float v0 = base[t * 2 + 1];
    float v1 = base[(t + 256) * 2 + 1];
    if (t == i)       v0 = -__builtin_inff();   // self-edge mask
    if (t + 256 == i) v1 = -__builtin_inff();

    float mx = fmaxf(v0, v1);
#pragma unroll
    for (int off = 32; off; off >>= 1) mx = fmaxf(mx, __shfl_xor(mx, off, 64));
    __shared__ float sm[4], ss[4];
    const int wave = t >> 6, lane = t & 63;
    if (lane == 0) sm[wave] = mx;
    __syncthreads();
    mx = fmaxf(fmaxf(sm[0], sm[1]), fmaxf(sm[2], sm[3]));

    const float e0 = __expf(v0 - mx), e1 = __expf(v1 - mx);
    float s = e0 + e1;
#pragma unroll
    for (int off = 32; off; off >>= 1) s += __shfl_xor(s, off, 64);
    if (lane == 0) ss[wave] = s;
    __syncthreads();
    s = ss[0] + ss[1] + ss[2] + ss[3];
    const float inv = 1.0f / s;

    float2* o2 = (float2*)base;
    o2[t]       = make_float2(t == i ? 1.f : 0.f,         e0 * inv);
    o2[t + 256] = make_float2((t + 256) == i ? 1.f : 0.f, e1 * inv);
}

// ---------------- host launch ----------------
extern "C" void kernel_launch(void* const* d_in, const int* in_sizes, int n_in,
                              void* d_out, int out_size, void* d_ws, size_t ws_size,
                              hipStream_t stream) {
    const float* x  = (const float*)d_in[0];
    // d_in[1] = W_id (pure eye broadcast; synthesized in-kernel)
    const float* w1 = (const float*)d_in[2];
    const float* b1 = (const float*)d_in[3];
    const float* w2 = (const float*)d_in[4];
    const float* b2 = (const float*)d_in[5];
    const float* w3 = (const float*)d_in[6];
    const float* b3 = (const float*)d_in[7];
    const float* w4 = (const float*)d_in[8];
    const float* b4 = (const float*)d_in[9];
    const float* w5 = (const float*)d_in[10];
    const float* b5 = (const float*)d_in[11];
    float* out = (float*)d_out;

    // ws: xb 524288 | w1f 24576 | w2f 36864 | w3f 18432 | w4fp 12288 (96x128 padded)
    char* ws = (char*)d_ws;
    __bf16*        xb   = (__bf16*)(ws);
    unsigned char* w1f  = (unsigned char*)(ws + 524288);
    unsigned char* w2f  = (unsigned char*)(ws + 548864);
    unsigned char* w3f  = (unsigned char*)(ws + 585728);
    unsigned char* w4fp = (unsigned char*)(ws + 604160);

    cvt_all<<<(88000 + 255) / 256, 256, 0, stream>>>(x, xb, w1, (int*)w1f,
                                                     w2, (int*)w2f, w3, (int*)w3f,
                                                     w4, w4fp);

    dim3 grid(NN / 16, NN / 4, NB);   // j-tiles, i-tiles, batch
    mlp_edges<<<grid, 256, 0, stream>>>(xb, w1f, b1, w2f, b2, w3f, b3, w4fp, b4,
                                        w5, b5, out);

    softmax_rows<<<NB * NN, 256, 0, stream>>>(out);
}